// Round 4
// baseline (360.748 us; speedup 1.0000x reference)
//
#include <hip/hip_runtime.h>
#include <hip/hip_bf16.h>

// ---------- problem constants ----------
#define BB 8
#define TT 2048
#define EE 1024
#define SS 2000
#define HH 150
#define HP 160     // padded hidden (GEMM N)
#define KP2 192    // padded K for layer-2 GEMMs
#define NT (BB*TT)     // 16384 tokens
#define NS (BB*SS)     // 16000 spans
#define SPAN_ELEMS ((long)NS*3072)

typedef __attribute__((ext_vector_type(8))) short short8;
typedef __attribute__((ext_vector_type(4))) float f32x4;

__device__ __forceinline__ float b2f(ushort u) {
    union { uint i; float f; } v; v.i = ((uint)u) << 16; return v.f;
}
__device__ __forceinline__ ushort f2b(float f) {
    uint x = __float_as_uint(f);
    uint r = (x + 0x7fffu + ((x >> 16) & 1u)) >> 16;   // RNE
    return (ushort)r;
}
// flag-dispatched scalar load: input tensors are either f32 or bf16
__device__ __forceinline__ float ldf(const void* p, long i, int f32) {
    return f32 ? ((const float*)p)[i] : b2f(((const ushort*)p)[i]);
}

// ---------- dtype detector ----------
// Interpret the first 64K ushorts of embeds as bf16. True bf16 N(0,1) data never
// has |x| >= 2^16 (exp field >= 0x8F). f32 data read as ushort pairs has uniform
// low-mantissa halves -> ~44% of them exceed that. One block, no atomics.
__global__ void detect_kernel(const ushort* __restrict__ p, int* __restrict__ flag) {
    __shared__ int sh;
    if (threadIdx.x == 0) sh = 0;
    __syncthreads();
    int found = 0;
    for (int i = threadIdx.x; i < 65536; i += 1024) {
        ushort v = p[i];
        if ((v & 0x7f80u) >= 0x4780u) found = 1;   // |bf16| >= 65536 (or inf/nan)
    }
    if (found) sh = 1;
    __syncthreads();
    if (threadIdx.x == 0) flag[0] = sh;            // 1 = inputs are f32
}

// ---------- weight prep: transpose + pad into [160][Kpad] bf16 ----------
__global__ void prep_kernel(const void* __restrict__ a_w1, const void* __restrict__ a_w2,
                            const void* __restrict__ s_w1, const void* __restrict__ s_w2,
                            const void* __restrict__ a_b1, const void* __restrict__ a_b2,
                            const void* __restrict__ s_b1, const void* __restrict__ s_b2,
                            const int* __restrict__ dflag,
                            ushort* __restrict__ a_w1t, ushort* __restrict__ a_w2t,
                            ushort* __restrict__ s_w1t, ushort* __restrict__ s_w2t,
                            float* __restrict__ biases /* 4 x 160 */)
{
    const int f32 = dflag[0];
    int j = blockIdx.x;          // output row (padded hidden idx) 0..159
    int which = blockIdx.y;
    int t = threadIdx.x;
    if (which == 0) {
        for (int k = t; k < EE; k += 256)
            a_w1t[j*EE + k] = (j < HH) ? f2b(ldf(a_w1, (long)k*HH + j, f32)) : (ushort)0;
    } else if (which == 1) {
        for (int k = t; k < KP2; k += 256)
            a_w2t[j*KP2 + k] = (j < HH && k < HH) ? f2b(ldf(a_w2, (long)k*HH + j, f32)) : (ushort)0;
    } else if (which == 2) {
        for (int k = t; k < 3*EE; k += 256)
            s_w1t[j*3*EE + k] = (j < HH) ? f2b(ldf(s_w1, (long)k*HH + j, f32)) : (ushort)0;
    } else if (which == 3) {
        for (int k = t; k < KP2; k += 256)
            s_w2t[j*KP2 + k] = (j < HH && k < HH) ? f2b(ldf(s_w2, (long)k*HH + j, f32)) : (ushort)0;
    } else {
        if (j == 0 && t < HP) {
            biases[t]        = (t < HH) ? ldf(a_b1, t, f32) : 0.f;
            biases[HP + t]   = (t < HH) ? ldf(a_b2, t, f32) : 0.f;
            biases[2*HP + t] = (t < HH) ? ldf(s_b1, t, f32) : 0.f;
            biases[3*HP + t] = (t < HH) ? ldf(s_b2, t, f32) : 0.f;
        }
    }
}

// ---------- MFMA GEMM: Out[M][ldo] = relu(A[M][K] @ W[K][150(pad160)] + b) ----------
// A dtype: bf16 if aflag==nullptr or *aflag==0, f32 if *aflag==1.
// Wt is [160][ldw] bf16 (transposed, zero-padded). Out is always bf16.
// LDS is fragment-major: [kgranule][row][8]: every short8 read 16B-aligned, conflict-free.
// If ldo > HP, cols HP..ldo-1 are zero-filled (consumed as K-pad downstream).
__global__ __launch_bounds__(256) void gemm_relu_kernel(
    const void* __restrict__ A, int lda, const int* __restrict__ aflag,
    const ushort* __restrict__ Wt, int ldw,
    const float* __restrict__ bias,
    ushort* __restrict__ Out, int ldo,
    int K)
{
    __shared__ __align__(16) ushort A2[8*64*8];    // 8 KB
    __shared__ __align__(16) ushort B2[8*160*8];   // 20 KB

    const int af32 = aflag ? aflag[0] : 0;
    const int t = threadIdx.x;
    const int row0 = blockIdx.x * 64;
    const int lane = t & 63;
    const int w = t >> 6;          // wave 0..3
    const int wr = w >> 1;         // 0..1  (rows wr*32)
    const int wc = w & 1;          // 0..1  (cols wc*80)
    const int l15 = lane & 15;
    const int kb = (lane >> 4) * 8;  // 0,8,16,24

    f32x4 acc[2][5];
#pragma unroll
    for (int m = 0; m < 2; ++m)
#pragma unroll
        for (int n = 0; n < 5; ++n) acc[m][n] = (f32x4){0.f, 0.f, 0.f, 0.f};

    const int arow = t >> 2;          // 0..63
    const int ag0 = (t & 3) * 2;      // A k-granule pair: 0,2,4,6

    for (int k0 = 0; k0 < K; k0 += 64) {
        // stage A tile 64 rows x 64 k (16 elements per thread)
        if (!af32) {
            const ushort* src = (const ushort*)A + (long)(row0 + arow) * lda + k0 + ag0 * 8;
            uint4 v0 = *(const uint4*)(src);
            uint4 v1 = *(const uint4*)(src + 8);
            *(uint4*)&A2[((ag0    ) * 64 + arow) * 8] = v0;
            *(uint4*)&A2[((ag0 + 1) * 64 + arow) * 8] = v1;
        } else {
            const float* src = (const float*)A + (long)(row0 + arow) * lda + k0 + ag0 * 8;
            ushort tmp[16];
#pragma unroll
            for (int j = 0; j < 16; ++j) tmp[j] = f2b(src[j]);
            *(uint4*)&A2[((ag0    ) * 64 + arow) * 8] = *(uint4*)&tmp[0];
            *(uint4*)&A2[((ag0 + 1) * 64 + arow) * 8] = *(uint4*)&tmp[8];
        }
        // stage B tile 160 rows(cols of W) x 64 k : 1280 granules of 8 elems
#pragma unroll
        for (int p = 0; p < 5; ++p) {
            int g = p * 256 + t;       // 0..1279
            int br = g >> 3;           // 0..159
            int bg = g & 7;            // k-granule 0..7
            uint4 v = *(const uint4*)(Wt + (long)br * ldw + k0 + bg * 8);
            *(uint4*)&B2[(bg * 160 + br) * 8] = v;
        }
        __syncthreads();
#pragma unroll
        for (int ks = 0; ks < 64; ks += 32) {
            const int kg = (ks + kb) >> 3;
            short8 af[2];
#pragma unroll
            for (int m = 0; m < 2; ++m)
                af[m] = *(const short8*)&A2[(kg * 64 + wr*32 + m*16 + l15) * 8];
#pragma unroll
            for (int n = 0; n < 5; ++n) {
                short8 bf = *(const short8*)&B2[(kg * 160 + wc*80 + n*16 + l15) * 8];
#pragma unroll
                for (int m = 0; m < 2; ++m)
                    acc[m][n] = __builtin_amdgcn_mfma_f32_16x16x32_bf16(af[m], bf, acc[m][n], 0, 0, 0);
            }
        }
        __syncthreads();
    }
    // epilogue: D row = (lane>>4)*4 + r, col = lane&15
#pragma unroll
    for (int m = 0; m < 2; ++m) {
        int rbase = row0 + wr*32 + m*16 + (lane >> 4) * 4;
#pragma unroll
        for (int n = 0; n < 5; ++n) {
            int col = wc*80 + n*16 + l15;
            float b = bias[col];
#pragma unroll
            for (int r = 0; r < 4; ++r) {
                float v = acc[m][n][r] + b;
                v = v > 0.f ? v : 0.f;
                Out[(long)(rbase + r) * ldo + col] = f2b(v);
            }
        }
    }
    // zero-fill the K-pad columns so downstream GEMMs never read garbage
    if (ldo > HP) {
        int r = t >> 2;                 // 0..63
        int c = HP + (t & 3) * 8;       // 160,168,176,184
        uint4 z = (uint4){0, 0, 0, 0};
        *(uint4*)(Out + (long)(row0 + r) * ldo + c) = z;
    }
}

// ---------- final 150-dot layer (no relu) ----------
// outf != nullptr: write f32 to outf[i] (attns path).
// else: write mention score i at element SPAN_ELEMS+i of outAll, dtype per dflag.
__global__ void dot150_kernel(const ushort* __restrict__ Hin,
                              const void* __restrict__ w3, const void* __restrict__ b3,
                              const int* __restrict__ dflag,
                              float* __restrict__ outf, void* __restrict__ outAll, int M)
{
    const int f32 = dflag[0];
    int i = blockIdx.x * 256 + threadIdx.x;
    if (i >= M) return;
    const ushort* row = Hin + (long)i * HP;
    float s = ldf(b3, 0, f32);
    for (int j = 0; j < HH; ++j) s += b2f(row[j]) * ldf(w3, j, f32);
    if (outf) outf[i] = s;
    else if (f32) ((float*)outAll)[SPAN_ELEMS + i] = s;
    else ((ushort*)outAll)[SPAN_ELEMS + i] = f2b(s);
}

// ---------- span assembly: [start_e | end_e | direct weighted sum] -> d_out ----------
// Span length <= 30: sum the rows directly in f32. One block per span, 256 threads,
// 4 columns per thread.
__global__ __launch_bounds__(256) void span_kernel(
    const void* __restrict__ embeds, const float* __restrict__ attns,
    const int* __restrict__ starts, const int* __restrict__ lens,
    void* __restrict__ out, const int* __restrict__ dflag)
{
    __shared__ float at[32];
    const int f32 = dflag[0];
    int s = blockIdx.x, b = blockIdx.y, t = threadIdx.x;
    int st = starts[b*SS + s];
    int len = lens[b*SS + s];       // inclusive span = st .. st+len (len+1 rows, <=30)
    int en = st + len;
    if (t < 30) at[t] = attns[b*TT + st + t];
    __syncthreads();
    int e4 = t * 4;
    long ebase = ((long)(b*TT + st)) * EE + e4;
    long eend  = ((long)(b*TT + en)) * EE + e4;
    long obase = ((long)(b*SS + s)) * 3072 + e4;
    if (!f32) {
        const ushort* E = (const ushort*)embeds;
        ushort* O = (ushort*)out;
        ushort4 se = *(const ushort4*)(E + ebase);
        ushort4 ed = *(const ushort4*)(E + eend);
        float ax = 0.f, ay = 0.f, az = 0.f, aw = 0.f;
        for (int i = 0; i <= len; ++i) {
            float a = at[i];
            ushort4 v = *(const ushort4*)(E + ebase + (long)i * EE);
            ax += b2f(v.x) * a; ay += b2f(v.y) * a;
            az += b2f(v.z) * a; aw += b2f(v.w) * a;
        }
        *(ushort4*)(O + obase) = se;
        *(ushort4*)(O + obase + 1024) = ed;
        ushort4 sm; sm.x = f2b(ax); sm.y = f2b(ay); sm.z = f2b(az); sm.w = f2b(aw);
        *(ushort4*)(O + obase + 2048) = sm;
    } else {
        const float* E = (const float*)embeds;
        float* O = (float*)out;
        float4 se = *(const float4*)(E + ebase);
        float4 ed = *(const float4*)(E + eend);
        float ax = 0.f, ay = 0.f, az = 0.f, aw = 0.f;
        for (int i = 0; i <= len; ++i) {
            float a = at[i];
            float4 v = *(const float4*)(E + ebase + (long)i * EE);
            ax += v.x * a; ay += v.y * a; az += v.z * a; aw += v.w * a;
        }
        *(float4*)(O + obase) = se;
        *(float4*)(O + obase + 1024) = ed;
        float4 sm = {ax, ay, az, aw};
        *(float4*)(O + obase + 2048) = sm;
    }
}

extern "C" void kernel_launch(void* const* d_in, const int* in_sizes, int n_in,
                              void* d_out, int out_size, void* d_ws, size_t ws_size,
                              hipStream_t stream)
{
    const void* embeds = d_in[0];
    const void* a_w1 = d_in[1];  const void* a_b1 = d_in[2];
    const void* a_w2 = d_in[3];  const void* a_b2 = d_in[4];
    const void* a_w3 = d_in[5];  const void* a_b3 = d_in[6];
    const void* s_w1 = d_in[7];  const void* s_b1 = d_in[8];
    const void* s_w2 = d_in[9];  const void* s_b2 = d_in[10];
    const void* s_w3 = d_in[11]; const void* s_b3 = d_in[12];
    const int* starts = (const int*)d_in[13];
    const int* lens   = (const int*)d_in[14];

    // workspace layout — total ~12.5 MB
    char* ws = (char*)d_ws;
    int*    dflag = (int*)ws;                  ws += 256;
    ushort* a_w1t = (ushort*)ws;               ws += (size_t)HP*EE*2;        // 320 KB
    ushort* a_w2t = (ushort*)ws;               ws += (size_t)HP*KP2*2;       // 60 KB
    ushort* s_w1t = (ushort*)ws;               ws += (size_t)HP*3*EE*2;      // 960 KB
    ushort* s_w2t = (ushort*)ws;               ws += (size_t)HP*KP2*2;       // 60 KB
    float*  biases = (float*)ws;               ws += (size_t)4*HP*4;         // 2.5 KB
    ushort* h1 = (ushort*)ws;                  ws += (size_t)NT*KP2*2;       // 6.3 MB
    ushort* h2 = (ushort*)ws;                  ws += (size_t)NT*HP*2;        // 5.25 MB
    float*  attns = (float*)ws;                ws += (size_t)NT*4;           // 64 KB

    // 0) dtype detect + weight transpose/pad
    detect_kernel<<<1, 1024, 0, stream>>>((const ushort*)embeds, dflag);
    prep_kernel<<<dim3(HP, 5), 256, 0, stream>>>(a_w1, a_w2, s_w1, s_w2,
                                                 a_b1, a_b2, s_b1, s_b2, dflag,
                                                 a_w1t, a_w2t, s_w1t, s_w2t, biases);
    // 1) attention MLP
    gemm_relu_kernel<<<NT/64, 256, 0, stream>>>(embeds, EE, dflag, a_w1t, EE, biases, h1, KP2, EE);
    gemm_relu_kernel<<<NT/64, 256, 0, stream>>>(h1, KP2, nullptr, a_w2t, KP2, biases + HP, h2, HP, KP2);
    dot150_kernel<<<NT/256, 256, 0, stream>>>(h2, a_w3, a_b3, dflag, attns, nullptr, NT);
    // 2) span embeds -> d_out (direct weighted sums, len <= 30)
    span_kernel<<<dim3(SS, BB), 256, 0, stream>>>(embeds, attns, starts, lens, d_out, dflag);
    // 3) mention MLP (reads span embeds back from d_out, dtype per flag)
    gemm_relu_kernel<<<NS/64, 256, 0, stream>>>(d_out, 3*EE, dflag, s_w1t, 3*EE, biases + 2*HP, h1, KP2, 3*EE);
    gemm_relu_kernel<<<NS/64, 256, 0, stream>>>(h1, KP2, nullptr, s_w2t, KP2, biases + 3*HP, h2, HP, KP2);
    dot150_kernel<<<(NS + 255)/256, 256, 0, stream>>>(h2, s_w3, s_b3, dflag, nullptr, d_out, NS);
}

// Round 5
// 259.317 us; speedup vs baseline: 1.3911x; 1.3911x over previous
//
#include <hip/hip_runtime.h>
#include <hip/hip_bf16.h>

// ---------- problem constants ----------
#define BB 8
#define TT 2048
#define EE 1024
#define SS 2000
#define HH 150
#define HP 160     // padded hidden (GEMM N)
#define KP2 192    // padded K for layer-2 GEMMs
#define NB 640     // big-GEMM N: [a_w1 | s_w1a | s_w1b | s_w1c] -> 4 x 160
#define NT (BB*TT)     // 16384 tokens
#define NS (BB*SS)     // 16000 spans
#define SPAN_ELEMS ((long)NS*3072)

typedef __attribute__((ext_vector_type(8))) short short8;
typedef __attribute__((ext_vector_type(4))) float f32x4;

__device__ __forceinline__ float b2f(ushort u) {
    union { uint i; float f; } v; v.i = ((uint)u) << 16; return v.f;
}
__device__ __forceinline__ ushort f2b(float f) {
    uint x = __float_as_uint(f);
    uint r = (x + 0x7fffu + ((x >> 16) & 1u)) >> 16;   // RNE
    return (ushort)r;
}
__device__ __forceinline__ float ldf(const void* p, long i, int f32) {
    return f32 ? ((const float*)p)[i] : b2f(((const ushort*)p)[i]);
}

// ---------- dtype detector (1 = inputs are f32, 0 = bf16) ----------
__global__ void detect_kernel(const ushort* __restrict__ p, int* __restrict__ flag) {
    __shared__ int sh;
    if (threadIdx.x == 0) sh = 0;
    __syncthreads();
    int found = 0;
    for (int i = threadIdx.x; i < 65536; i += 1024) {
        ushort v = p[i];
        if ((v & 0x7f80u) >= 0x4780u) found = 1;   // |bf16| >= 65536 (or inf/nan)
    }
    if (found) sh = 1;
    __syncthreads();
    if (threadIdx.x == 0) flag[0] = sh;
}

// ---------- weight prep ----------
// Wbig [640][1024] bf16: row j (part p=j/160, jj=j%160):
//   p=0 -> a_w1[:,jj] ; p=1..3 -> s_w1[(p-1)*1024 + k, jj]   (0 for jj>=150)
// a_w2t/s_w2t [160][192] bf16 transposed+padded. biases 4x160 f32.
__global__ void prep_kernel(const void* __restrict__ a_w1, const void* __restrict__ s_w1,
                            const void* __restrict__ a_w2, const void* __restrict__ s_w2,
                            const void* __restrict__ a_b1, const void* __restrict__ a_b2,
                            const void* __restrict__ s_b1, const void* __restrict__ s_b2,
                            const int* __restrict__ dflag,
                            ushort* __restrict__ Wbig,
                            ushort* __restrict__ a_w2t, ushort* __restrict__ s_w2t,
                            float* __restrict__ biases)
{
    const int f32 = dflag[0];
    int j = blockIdx.x;
    int which = blockIdx.y;
    int t = threadIdx.x;
    if (which == 0) {          // j in 0..639
        int p = j / 160, jj = j - p * 160;
        for (int k = t; k < EE; k += 256) {
            float v = 0.f;
            if (jj < HH)
                v = (p == 0) ? ldf(a_w1, (long)k * HH + jj, f32)
                             : ldf(s_w1, ((long)(p - 1) * EE + k) * HH + jj, f32);
            Wbig[(long)j * EE + k] = f2b(v);
        }
    } else if (which == 1) {
        if (j < HP)
            for (int k = t; k < KP2; k += 256)
                a_w2t[j * KP2 + k] = (j < HH && k < HH) ? f2b(ldf(a_w2, (long)k * HH + j, f32)) : (ushort)0;
    } else if (which == 2) {
        if (j < HP)
            for (int k = t; k < KP2; k += 256)
                s_w2t[j * KP2 + k] = (j < HH && k < HH) ? f2b(ldf(s_w2, (long)k * HH + j, f32)) : (ushort)0;
    } else {
        if (j == 0 && t < HP) {
            biases[t]          = (t < HH) ? ldf(a_b1, t, f32) : 0.f;
            biases[HP + t]     = (t < HH) ? ldf(a_b2, t, f32) : 0.f;
            biases[2*HP + t]   = (t < HH) ? ldf(s_b1, t, f32) : 0.f;
            biases[3*HP + t]   = (t < HH) ? ldf(s_b2, t, f32) : 0.f;
        }
    }
}

// ---------- big token GEMM: embeds[16384][1024] @ Wbig^T -> 4 col-groups ----------
// cg = blockIdx.y: cg==0 -> h1a (bias a_b1 + relu, ldo=192, pad-fill 160..191)
//                  cg>=1 -> Pabc cols (cg-1)*160.. (raw f32->bf16, ld=480)
__global__ __launch_bounds__(256) void big_gemm_kernel(
    const void* __restrict__ A, const int* __restrict__ dflag,
    const ushort* __restrict__ Wbig,
    const float* __restrict__ biases,
    ushort* __restrict__ h1a, ushort* __restrict__ Pabc)
{
    __shared__ __align__(16) ushort A2[8*64*8];    // 8 KB
    __shared__ __align__(16) ushort B2[8*160*8];   // 20 KB

    const int af32 = dflag[0];
    const int t = threadIdx.x;
    const int row0 = blockIdx.x * 64;
    const int cg = blockIdx.y;
    const int cgbase = cg * 160;
    const int lane = t & 63;
    const int w = t >> 6;
    const int wr = w >> 1;
    const int wc = w & 1;
    const int l15 = lane & 15;
    const int kb = (lane >> 4) * 8;

    f32x4 acc[2][5];
#pragma unroll
    for (int m = 0; m < 2; ++m)
#pragma unroll
        for (int n = 0; n < 5; ++n) acc[m][n] = (f32x4){0.f, 0.f, 0.f, 0.f};

    const int arow = t >> 2;
    const int ag0 = (t & 3) * 2;

    for (int k0 = 0; k0 < EE; k0 += 64) {
        if (!af32) {
            const ushort* src = (const ushort*)A + (long)(row0 + arow) * EE + k0 + ag0 * 8;
            *(uint4*)&A2[((ag0    ) * 64 + arow) * 8] = *(const uint4*)(src);
            *(uint4*)&A2[((ag0 + 1) * 64 + arow) * 8] = *(const uint4*)(src + 8);
        } else {
            const float* src = (const float*)A + (long)(row0 + arow) * EE + k0 + ag0 * 8;
            ushort tmp[16];
#pragma unroll
            for (int j = 0; j < 16; ++j) tmp[j] = f2b(src[j]);
            *(uint4*)&A2[((ag0    ) * 64 + arow) * 8] = *(uint4*)&tmp[0];
            *(uint4*)&A2[((ag0 + 1) * 64 + arow) * 8] = *(uint4*)&tmp[8];
        }
#pragma unroll
        for (int p = 0; p < 5; ++p) {
            int gg = p * 256 + t;
            int br = gg >> 3;
            int bg = gg & 7;
            uint4 v = *(const uint4*)(Wbig + (long)(cgbase + br) * EE + k0 + bg * 8);
            *(uint4*)&B2[(bg * 160 + br) * 8] = v;
        }
        __syncthreads();
#pragma unroll
        for (int ks = 0; ks < 64; ks += 32) {
            const int kg = (ks + kb) >> 3;
            short8 af[2];
#pragma unroll
            for (int m = 0; m < 2; ++m)
                af[m] = *(const short8*)&A2[(kg * 64 + wr*32 + m*16 + l15) * 8];
#pragma unroll
            for (int n = 0; n < 5; ++n) {
                short8 bf = *(const short8*)&B2[(kg * 160 + wc*80 + n*16 + l15) * 8];
#pragma unroll
                for (int m = 0; m < 2; ++m)
                    acc[m][n] = __builtin_amdgcn_mfma_f32_16x16x32_bf16(af[m], bf, acc[m][n], 0, 0, 0);
            }
        }
        __syncthreads();
    }
    if (cg == 0) {
#pragma unroll
        for (int m = 0; m < 2; ++m) {
            int rbase = row0 + wr*32 + m*16 + (lane >> 4) * 4;
#pragma unroll
            for (int n = 0; n < 5; ++n) {
                int col = wc*80 + n*16 + l15;
                float b = biases[col];
#pragma unroll
                for (int r = 0; r < 4; ++r) {
                    float v = acc[m][n][r] + b;
                    v = v > 0.f ? v : 0.f;
                    h1a[(long)(rbase + r) * KP2 + col] = f2b(v);
                }
            }
        }
        int r = t >> 2;
        int c = HP + (t & 3) * 8;
        *(uint4*)(h1a + (long)(row0 + r) * KP2 + c) = (uint4){0,0,0,0};
    } else {
        int cb = (cg - 1) * 160;
#pragma unroll
        for (int m = 0; m < 2; ++m) {
            int rbase = row0 + wr*32 + m*16 + (lane >> 4) * 4;
#pragma unroll
            for (int n = 0; n < 5; ++n) {
                int col = cb + wc*80 + n*16 + l15;
#pragma unroll
                for (int r = 0; r < 4; ++r)
                    Pabc[(long)(rbase + r) * 480 + col] = f2b(acc[m][n][r]);
            }
        }
    }
}

// ---------- layer-2 GEMM: Out[M][160] = relu(A[M][192] @ Wt + b) (A bf16) ----------
__global__ __launch_bounds__(256) void gemm_relu_kernel(
    const ushort* __restrict__ A,
    const ushort* __restrict__ Wt,
    const float* __restrict__ bias,
    ushort* __restrict__ Out)
{
    __shared__ __align__(16) ushort A2[8*64*8];
    __shared__ __align__(16) ushort B2[8*160*8];

    const int t = threadIdx.x;
    const int row0 = blockIdx.x * 64;
    const int lane = t & 63;
    const int w = t >> 6;
    const int wr = w >> 1;
    const int wc = w & 1;
    const int l15 = lane & 15;
    const int kb = (lane >> 4) * 8;

    f32x4 acc[2][5];
#pragma unroll
    for (int m = 0; m < 2; ++m)
#pragma unroll
        for (int n = 0; n < 5; ++n) acc[m][n] = (f32x4){0.f, 0.f, 0.f, 0.f};

    const int arow = t >> 2;
    const int ag0 = (t & 3) * 2;

    for (int k0 = 0; k0 < KP2; k0 += 64) {
        {
            const ushort* src = A + (long)(row0 + arow) * KP2 + k0 + ag0 * 8;
            *(uint4*)&A2[((ag0    ) * 64 + arow) * 8] = *(const uint4*)(src);
            *(uint4*)&A2[((ag0 + 1) * 64 + arow) * 8] = *(const uint4*)(src + 8);
        }
#pragma unroll
        for (int p = 0; p < 5; ++p) {
            int gg = p * 256 + t;
            int br = gg >> 3;
            int bg = gg & 7;
            uint4 v = *(const uint4*)(Wt + (long)br * KP2 + k0 + bg * 8);
            *(uint4*)&B2[(bg * 160 + br) * 8] = v;
        }
        __syncthreads();
#pragma unroll
        for (int ks = 0; ks < 64; ks += 32) {
            const int kg = (ks + kb) >> 3;
            short8 af[2];
#pragma unroll
            for (int m = 0; m < 2; ++m)
                af[m] = *(const short8*)&A2[(kg * 64 + wr*32 + m*16 + l15) * 8];
#pragma unroll
            for (int n = 0; n < 5; ++n) {
                short8 bf = *(const short8*)&B2[(kg * 160 + wc*80 + n*16 + l15) * 8];
#pragma unroll
                for (int m = 0; m < 2; ++m)
                    acc[m][n] = __builtin_amdgcn_mfma_f32_16x16x32_bf16(af[m], bf, acc[m][n], 0, 0, 0);
            }
        }
        __syncthreads();
    }
#pragma unroll
    for (int m = 0; m < 2; ++m) {
        int rbase = row0 + wr*32 + m*16 + (lane >> 4) * 4;
#pragma unroll
        for (int n = 0; n < 5; ++n) {
            int col = wc*80 + n*16 + l15;
            float b = bias[col];
#pragma unroll
            for (int r = 0; r < 4; ++r) {
                float v = acc[m][n][r] + b;
                v = v > 0.f ? v : 0.f;
                Out[(long)(rbase + r) * HP + col] = f2b(v);
            }
        }
    }
}

// ---------- final 150-dot layer (no relu) ----------
__global__ void dot150_kernel(const ushort* __restrict__ Hin,
                              const void* __restrict__ w3, const void* __restrict__ b3,
                              const int* __restrict__ dflag,
                              float* __restrict__ outf, void* __restrict__ outAll, int M)
{
    const int f32 = dflag[0];
    int i = blockIdx.x * 256 + threadIdx.x;
    if (i >= M) return;
    const ushort* row = Hin + (long)i * HP;
    float s = ldf(b3, 0, f32);
    for (int j = 0; j < HH; ++j) s += b2f(row[j]) * ldf(w3, j, f32);
    if (outf) outf[i] = s;
    else if (f32) ((float*)outAll)[SPAN_ELEMS + i] = s;
    else ((ushort*)outAll)[SPAN_ELEMS + i] = f2b(s);
}

// ---------- span: out0 = [start_e|end_e|span_sum]; h1m = relu(Pa+Pb+Σa·Pc+b) ----------
__global__ __launch_bounds__(256) void span_kernel(
    const void* __restrict__ embeds, const float* __restrict__ attns,
    const int* __restrict__ starts, const int* __restrict__ lens,
    void* __restrict__ out, const int* __restrict__ dflag,
    const ushort* __restrict__ Pabc, const float* __restrict__ biases2,
    ushort* __restrict__ h1m)
{
    __shared__ float at[32];
    const int f32 = dflag[0];
    int s = blockIdx.x, b = blockIdx.y, t = threadIdx.x;
    int st = starts[b*SS + s];
    int len = lens[b*SS + s];       // inclusive span st..st+len, len+1 <= 30 rows
    int en = st + len;
    if (t < 30) at[t] = attns[b*TT + st + t];
    __syncthreads();
    // ---- phase A: span_embeds -> out0 ----
    int e4 = t * 4;
    long ebase = ((long)(b*TT + st)) * EE + e4;
    long eend  = ((long)(b*TT + en)) * EE + e4;
    long obase = ((long)(b*SS + s)) * 3072 + e4;
    if (!f32) {
        const ushort* E = (const ushort*)embeds;
        ushort* O = (ushort*)out;
        ushort4 se = *(const ushort4*)(E + ebase);
        ushort4 ed = *(const ushort4*)(E + eend);
        float ax = 0.f, ay = 0.f, az = 0.f, aw = 0.f;
        for (int i = 0; i <= len; ++i) {
            float a = at[i];
            ushort4 v = *(const ushort4*)(E + ebase + (long)i * EE);
            ax += b2f(v.x) * a; ay += b2f(v.y) * a;
            az += b2f(v.z) * a; aw += b2f(v.w) * a;
        }
        *(ushort4*)(O + obase) = se;
        *(ushort4*)(O + obase + 1024) = ed;
        ushort4 sm; sm.x = f2b(ax); sm.y = f2b(ay); sm.z = f2b(az); sm.w = f2b(aw);
        *(ushort4*)(O + obase + 2048) = sm;
    } else {
        const float* E = (const float*)embeds;
        float* O = (float*)out;
        float4 se = *(const float4*)(E + ebase);
        float4 ed = *(const float4*)(E + eend);
        float ax = 0.f, ay = 0.f, az = 0.f, aw = 0.f;
        for (int i = 0; i <= len; ++i) {
            float a = at[i];
            float4 v = *(const float4*)(E + ebase + (long)i * EE);
            ax += v.x * a; ay += v.y * a; az += v.z * a; aw += v.w * a;
        }
        *(float4*)(O + obase) = se;
        *(float4*)(O + obase + 1024) = ed;
        float4 sm = {ax, ay, az, aw};
        *(float4*)(O + obase + 2048) = sm;
    }
    // ---- phase B: mention-layer-1 row via linearity ----
    long rowi = (long)(b*SS + s);
    if (t < HP) {
        float acc = biases2[t]
                  + b2f(Pabc[((long)(b*TT + st)) * 480 + t])
                  + b2f(Pabc[((long)(b*TT + en)) * 480 + 160 + t]);
        const ushort* pc = Pabc + ((long)(b*TT + st)) * 480 + 320 + t;
        for (int i = 0; i <= len; ++i) acc += at[i] * b2f(pc[(long)i * 480]);
        acc = acc > 0.f ? acc : 0.f;
        h1m[rowi * KP2 + t] = f2b(acc);
    } else if (t < KP2) {
        h1m[rowi * KP2 + t] = 0;
    }
}

extern "C" void kernel_launch(void* const* d_in, const int* in_sizes, int n_in,
                              void* d_out, int out_size, void* d_ws, size_t ws_size,
                              hipStream_t stream)
{
    const void* embeds = d_in[0];
    const void* a_w1 = d_in[1];  const void* a_b1 = d_in[2];
    const void* a_w2 = d_in[3];  const void* a_b2 = d_in[4];
    const void* a_w3 = d_in[5];  const void* a_b3 = d_in[6];
    const void* s_w1 = d_in[7];  const void* s_b1 = d_in[8];
    const void* s_w2 = d_in[9];  const void* s_b2 = d_in[10];
    const void* s_w3 = d_in[11]; const void* s_b3 = d_in[12];
    const int* starts = (const int*)d_in[13];
    const int* lens   = (const int*)d_in[14];

    // workspace layout — ~40 MB
    char* ws = (char*)d_ws;
    int*    dflag = (int*)ws;                  ws += 256;
    ushort* Wbig  = (ushort*)ws;               ws += (size_t)NB*EE*2;        // 1.31 MB
    ushort* a_w2t = (ushort*)ws;               ws += (size_t)HP*KP2*2;       // 60 KB
    ushort* s_w2t = (ushort*)ws;               ws += (size_t)HP*KP2*2;       // 60 KB
    float*  biases = (float*)ws;               ws += (size_t)4*HP*4;         // 2.5 KB
    ushort* h1a  = (ushort*)ws;                ws += (size_t)NT*KP2*2;       // 6.3 MB
    ushort* Pabc = (ushort*)ws;                ws += (size_t)NT*480*2;       // 15.7 MB
    ushort* h2a  = (ushort*)ws;                ws += (size_t)NT*HP*2;        // 5.25 MB
    float*  attns = (float*)ws;                ws += (size_t)NT*4;           // 64 KB
    ushort* h1m  = (ushort*)ws;                ws += (size_t)NS*KP2*2;       // 6.1 MB
    ushort* h2m  = (ushort*)ws;                ws += (size_t)NS*HP*2;        // 5.1 MB

    detect_kernel<<<1, 1024, 0, stream>>>((const ushort*)embeds, dflag);
    prep_kernel<<<dim3(NB, 4), 256, 0, stream>>>(a_w1, s_w1, a_w2, s_w2,
                                                 a_b1, a_b2, s_b1, s_b2, dflag,
                                                 Wbig, a_w2t, s_w2t, biases);
    // token-level fused layer-1 GEMM (attn h1 + mention projections Pa,Pb,Pc)
    big_gemm_kernel<<<dim3(NT/64, 4), 256, 0, stream>>>(embeds, dflag, Wbig, biases, h1a, Pabc);
    // attn layer-2 + score
    gemm_relu_kernel<<<NT/64, 256, 0, stream>>>(h1a, a_w2t, biases + HP, h2a);
    dot150_kernel<<<NT/256, 256, 0, stream>>>(h2a, a_w3, a_b3, dflag, attns, nullptr, NT);
    // spans: output 0 + mention h1 via linearity
    span_kernel<<<dim3(SS, BB), 256, 0, stream>>>(embeds, attns, starts, lens, d_out, dflag,
                                                  Pabc, biases + 2*HP, h1m);
    // mention layer-2 + score
    gemm_relu_kernel<<<NS/64, 256, 0, stream>>>(h1m, s_w2t, biases + 3*HP, h2m);
    dot150_kernel<<<(NS + 255)/256, 256, 0, stream>>>(h2m, s_w3, s_b3, dflag, nullptr, d_out, NS);
}

// Round 7
// 171.559 us; speedup vs baseline: 2.1028x; 1.5115x over previous
//
#include <hip/hip_runtime.h>
#include <hip/hip_bf16.h>

// ---------- problem constants ----------
#define BB 8
#define TT 2048
#define EE 1024
#define SS 2000
#define HH 150
#define HP 160     // padded hidden (GEMM N)
#define KP2 192    // padded K for layer-2 GEMMs
#define NB 640     // big-GEMM N: [a_w1 | s_w1a | s_w1b | s_w1c] -> 4 x 160
#define NT (BB*TT)     // 16384 tokens
#define NS (BB*SS)     // 16000 spans
#define SPAN_ELEMS ((long)NS*3072)

typedef __attribute__((ext_vector_type(8))) short short8;
typedef __attribute__((ext_vector_type(4))) float f32x4;
typedef __attribute__((ext_vector_type(4))) ushort u16x4;

__device__ __forceinline__ float b2f(ushort u) {
    union { uint i; float f; } v; v.i = ((uint)u) << 16; return v.f;
}
__device__ __forceinline__ ushort f2b(float f) {
    uint x = __float_as_uint(f);
    uint r = (x + 0x7fffu + ((x >> 16) & 1u)) >> 16;   // RNE
    return (ushort)r;
}
__device__ __forceinline__ float ldf(const void* p, long i, int f32) {
    return f32 ? ((const float*)p)[i] : b2f(((const ushort*)p)[i]);
}

// ---------- dtype detector (1 = inputs are f32, 0 = bf16) ----------
__global__ void detect_kernel(const ushort* __restrict__ p, int* __restrict__ flag) {
    __shared__ int sh;
    if (threadIdx.x == 0) sh = 0;
    __syncthreads();
    int found = 0;
    for (int i = threadIdx.x; i < 65536; i += 1024) {
        ushort v = p[i];
        if ((v & 0x7f80u) >= 0x4780u) found = 1;   // |bf16| >= 65536 (or inf/nan)
    }
    if (found) sh = 1;
    __syncthreads();
    if (threadIdx.x == 0) flag[0] = sh;
}

// ---------- weight prep ----------
__global__ void prep_kernel(const void* __restrict__ a_w1, const void* __restrict__ s_w1,
                            const void* __restrict__ a_w2, const void* __restrict__ s_w2,
                            const void* __restrict__ a_b1, const void* __restrict__ a_b2,
                            const void* __restrict__ s_b1, const void* __restrict__ s_b2,
                            const int* __restrict__ dflag,
                            ushort* __restrict__ Wbig,
                            ushort* __restrict__ a_w2t, ushort* __restrict__ s_w2t,
                            float* __restrict__ biases)
{
    const int f32 = dflag[0];
    int j = blockIdx.x;
    int which = blockIdx.y;
    int t = threadIdx.x;
    if (which == 0) {          // j in 0..639
        int p = j / 160, jj = j - p * 160;
        for (int k = t; k < EE; k += 256) {
            float v = 0.f;
            if (jj < HH)
                v = (p == 0) ? ldf(a_w1, (long)k * HH + jj, f32)
                             : ldf(s_w1, ((long)(p - 1) * EE + k) * HH + jj, f32);
            Wbig[(long)j * EE + k] = f2b(v);
        }
    } else if (which == 1) {
        if (j < HP)
            for (int k = t; k < KP2; k += 256)
                a_w2t[j * KP2 + k] = (j < HH && k < HH) ? f2b(ldf(a_w2, (long)k * HH + j, f32)) : (ushort)0;
    } else if (which == 2) {
        if (j < HP)
            for (int k = t; k < KP2; k += 256)
                s_w2t[j * KP2 + k] = (j < HH && k < HH) ? f2b(ldf(s_w2, (long)k * HH + j, f32)) : (ushort)0;
    } else {
        if (j == 0 && t < HP) {
            biases[t]          = (t < HH) ? ldf(a_b1, t, f32) : 0.f;
            biases[HP + t]     = (t < HH) ? ldf(a_b2, t, f32) : 0.f;
            biases[2*HP + t]   = (t < HH) ? ldf(s_b1, t, f32) : 0.f;
            biases[3*HP + t]   = (t < HH) ? ldf(s_b2, t, f32) : 0.f;
        }
    }
}

// ---------- big token GEMM: embeds[16384][1024] @ Wbig^T -> 4 col-groups ----------
__global__ __launch_bounds__(256) void big_gemm_kernel(
    const void* __restrict__ A, const int* __restrict__ dflag,
    const ushort* __restrict__ Wbig,
    const float* __restrict__ biases,
    ushort* __restrict__ h1a, ushort* __restrict__ Pabc)
{
    __shared__ __align__(16) ushort A2[8*64*8];    // 8 KB
    __shared__ __align__(16) ushort B2[8*160*8];   // 20 KB

    const int af32 = dflag[0];
    const int t = threadIdx.x;
    const int row0 = blockIdx.x * 64;
    const int cg = blockIdx.y;
    const int cgbase = cg * 160;
    const int lane = t & 63;
    const int w = t >> 6;
    const int wr = w >> 1;
    const int wc = w & 1;
    const int l15 = lane & 15;
    const int kb = (lane >> 4) * 8;

    f32x4 acc[2][5];
#pragma unroll
    for (int m = 0; m < 2; ++m)
#pragma unroll
        for (int n = 0; n < 5; ++n) acc[m][n] = (f32x4){0.f, 0.f, 0.f, 0.f};

    const int arow = t >> 2;
    const int ag0 = (t & 3) * 2;

    for (int k0 = 0; k0 < EE; k0 += 64) {
        if (!af32) {
            const ushort* src = (const ushort*)A + (long)(row0 + arow) * EE + k0 + ag0 * 8;
            *(uint4*)&A2[((ag0    ) * 64 + arow) * 8] = *(const uint4*)(src);
            *(uint4*)&A2[((ag0 + 1) * 64 + arow) * 8] = *(const uint4*)(src + 8);
        } else {
            const float* src = (const float*)A + (long)(row0 + arow) * EE + k0 + ag0 * 8;
            ushort tmp[16];
#pragma unroll
            for (int j = 0; j < 16; ++j) tmp[j] = f2b(src[j]);
            *(uint4*)&A2[((ag0    ) * 64 + arow) * 8] = *(uint4*)&tmp[0];
            *(uint4*)&A2[((ag0 + 1) * 64 + arow) * 8] = *(uint4*)&tmp[8];
        }
#pragma unroll
        for (int p = 0; p < 5; ++p) {
            int gg = p * 256 + t;
            int br = gg >> 3;
            int bg = gg & 7;
            uint4 v = *(const uint4*)(Wbig + (long)(cgbase + br) * EE + k0 + bg * 8);
            *(uint4*)&B2[(bg * 160 + br) * 8] = v;
        }
        __syncthreads();
#pragma unroll
        for (int ks = 0; ks < 64; ks += 32) {
            const int kg = (ks + kb) >> 3;
            short8 af[2];
#pragma unroll
            for (int m = 0; m < 2; ++m)
                af[m] = *(const short8*)&A2[(kg * 64 + wr*32 + m*16 + l15) * 8];
#pragma unroll
            for (int n = 0; n < 5; ++n) {
                short8 bf = *(const short8*)&B2[(kg * 160 + wc*80 + n*16 + l15) * 8];
#pragma unroll
                for (int m = 0; m < 2; ++m)
                    acc[m][n] = __builtin_amdgcn_mfma_f32_16x16x32_bf16(af[m], bf, acc[m][n], 0, 0, 0);
            }
        }
        __syncthreads();
    }
    if (cg == 0) {
#pragma unroll
        for (int m = 0; m < 2; ++m) {
            int rbase = row0 + wr*32 + m*16 + (lane >> 4) * 4;
#pragma unroll
            for (int n = 0; n < 5; ++n) {
                int col = wc*80 + n*16 + l15;
                float b = biases[col];
#pragma unroll
                for (int r = 0; r < 4; ++r) {
                    float v = acc[m][n][r] + b;
                    v = v > 0.f ? v : 0.f;
                    h1a[(long)(rbase + r) * KP2 + col] = f2b(v);
                }
            }
        }
        int r = t >> 2;
        int c = HP + (t & 3) * 8;
        *(uint4*)(h1a + (long)(row0 + r) * KP2 + c) = (uint4){0,0,0,0};
    } else {
        int cb = (cg - 1) * 160;
#pragma unroll
        for (int m = 0; m < 2; ++m) {
            int rbase = row0 + wr*32 + m*16 + (lane >> 4) * 4;
#pragma unroll
            for (int n = 0; n < 5; ++n) {
                int col = cb + wc*80 + n*16 + l15;
#pragma unroll
                for (int r = 0; r < 4; ++r)
                    Pabc[(long)(rbase + r) * 480 + col] = f2b(acc[m][n][r]);
            }
        }
    }
}

// ---------- fused layer-2 GEMM + score dot ----------
// score[row] = b3 + sum_col relu(A[row]@Wt[col] + bias[col]) * w3[col]
__global__ __launch_bounds__(256) void gemm_relu_dot_kernel(
    const ushort* __restrict__ A,
    const ushort* __restrict__ Wt,
    const float* __restrict__ bias,
    const void* __restrict__ w3, const void* __restrict__ b3,
    const int* __restrict__ dflag,
    float* __restrict__ outf, void* __restrict__ outAll)
{
    __shared__ __align__(16) ushort A2[8*64*8];
    __shared__ __align__(16) ushort B2[8*160*8];
    __shared__ float w3lds[HP];
    __shared__ float red[64][2];

    const int f32 = dflag[0];
    const int t = threadIdx.x;
    const int row0 = blockIdx.x * 64;
    const int lane = t & 63;
    const int w = t >> 6;
    const int wr = w >> 1;
    const int wc = w & 1;
    const int l15 = lane & 15;
    const int kb = (lane >> 4) * 8;

    if (t < HP) w3lds[t] = (t < HH) ? ldf(w3, t, f32) : 0.f;

    f32x4 acc[2][5];
#pragma unroll
    for (int m = 0; m < 2; ++m)
#pragma unroll
        for (int n = 0; n < 5; ++n) acc[m][n] = (f32x4){0.f, 0.f, 0.f, 0.f};

    const int arow = t >> 2;
    const int ag0 = (t & 3) * 2;

    for (int k0 = 0; k0 < KP2; k0 += 64) {
        {
            const ushort* src = A + (long)(row0 + arow) * KP2 + k0 + ag0 * 8;
            *(uint4*)&A2[((ag0    ) * 64 + arow) * 8] = *(const uint4*)(src);
            *(uint4*)&A2[((ag0 + 1) * 64 + arow) * 8] = *(const uint4*)(src + 8);
        }
#pragma unroll
        for (int p = 0; p < 5; ++p) {
            int gg = p * 256 + t;
            int br = gg >> 3;
            int bg = gg & 7;
            uint4 v = *(const uint4*)(Wt + (long)br * KP2 + k0 + bg * 8);
            *(uint4*)&B2[(bg * 160 + br) * 8] = v;
        }
        __syncthreads();
#pragma unroll
        for (int ks = 0; ks < 64; ks += 32) {
            const int kg = (ks + kb) >> 3;
            short8 af[2];
#pragma unroll
            for (int m = 0; m < 2; ++m)
                af[m] = *(const short8*)&A2[(kg * 64 + wr*32 + m*16 + l15) * 8];
#pragma unroll
            for (int n = 0; n < 5; ++n) {
                short8 bf = *(const short8*)&B2[(kg * 160 + wc*80 + n*16 + l15) * 8];
#pragma unroll
                for (int m = 0; m < 2; ++m)
                    acc[m][n] = __builtin_amdgcn_mfma_f32_16x16x32_bf16(af[m], bf, acc[m][n], 0, 0, 0);
            }
        }
        __syncthreads();
    }
    // epilogue: relu + dot(w3) fused, no h2 materialization
    float w3c[5];
    float bc[5];
#pragma unroll
    for (int n = 0; n < 5; ++n) {
        int col = wc*80 + n*16 + l15;
        w3c[n] = w3lds[col];
        bc[n] = bias[col];
    }
    float p[2][4];
#pragma unroll
    for (int m = 0; m < 2; ++m)
#pragma unroll
        for (int r = 0; r < 4; ++r) {
            float s = 0.f;
#pragma unroll
            for (int n = 0; n < 5; ++n) {
                float v = acc[m][n][r] + bc[n];
                v = v > 0.f ? v : 0.f;
                s += v * w3c[n];
            }
            p[m][r] = s;
        }
#pragma unroll
    for (int mask = 1; mask < 16; mask <<= 1)
#pragma unroll
        for (int m = 0; m < 2; ++m)
#pragma unroll
            for (int r = 0; r < 4; ++r)
                p[m][r] += __shfl_xor(p[m][r], mask, 16);
    if (l15 == 0) {
        int g = lane >> 4;
#pragma unroll
        for (int m = 0; m < 2; ++m)
#pragma unroll
            for (int r = 0; r < 4; ++r)
                red[wr*32 + m*16 + g*4 + r][wc] = p[m][r];
    }
    __syncthreads();
    if (t < 64) {
        int row = row0 + t;
        float s = red[t][0] + red[t][1] + ldf(b3, 0, f32);
        if (outf) outf[row] = s;
        else if (f32) ((float*)outAll)[SPAN_ELEMS + row] = s;
        else ((ushort*)outAll)[SPAN_ELEMS + row] = f2b(s);
    }
}

// ---------- span: out0 = [start_e|end_e|span_sum]; h1m = relu(Pa+Pb+Σa·Pc+b) ----------
// 1D grid 16000 with bijective XCD swizzle: XCD k owns batch k's spans in sorted order.
__global__ __launch_bounds__(256) void span_kernel(
    const void* __restrict__ embeds, const float* __restrict__ attns,
    const int* __restrict__ starts, const int* __restrict__ lens,
    void* __restrict__ out, const int* __restrict__ dflag,
    const ushort* __restrict__ Pabc, const float* __restrict__ biases2,
    ushort* __restrict__ h1m)
{
    __shared__ float at[32];
    const int f32 = dflag[0];
    int bid = blockIdx.x;
    int swz = (bid & 7) * (NS / 8) + (bid >> 3);   // bijective (16000 % 8 == 0)
    int b = swz / SS, s = swz - b * SS;
    int t = threadIdx.x;
    int st = starts[b*SS + s];
    int len = lens[b*SS + s];       // inclusive span st..st+len, len+1 <= 30 rows
    int en = st + len;
    if (t < 30) at[t] = attns[b*TT + st + t];
    __syncthreads();
    // ---- phase A: span_embeds -> out (non-temporal stores keep L2 for gather) ----
    int e4 = t * 4;
    long ebase = ((long)(b*TT + st)) * EE + e4;
    long eend  = ((long)(b*TT + en)) * EE + e4;
    long obase = ((long)(b*SS + s)) * 3072 + e4;
    if (!f32) {
        const ushort* E = (const ushort*)embeds;
        ushort* O = (ushort*)out;
        u16x4 se = *(const u16x4*)(E + ebase);
        u16x4 ed = *(const u16x4*)(E + eend);
        float ax = 0.f, ay = 0.f, az = 0.f, aw = 0.f;
        for (int i = 0; i <= len; ++i) {
            float a = at[i];
            u16x4 v = *(const u16x4*)(E + ebase + (long)i * EE);
            ax += b2f(v.x) * a; ay += b2f(v.y) * a;
            az += b2f(v.z) * a; aw += b2f(v.w) * a;
        }
        u16x4 sm; sm.x = f2b(ax); sm.y = f2b(ay); sm.z = f2b(az); sm.w = f2b(aw);
        __builtin_nontemporal_store(se, (u16x4*)(O + obase));
        __builtin_nontemporal_store(ed, (u16x4*)(O + obase + 1024));
        __builtin_nontemporal_store(sm, (u16x4*)(O + obase + 2048));
    } else {
        const float* E = (const float*)embeds;
        float* O = (float*)out;
        f32x4 se = *(const f32x4*)(E + ebase);
        f32x4 ed = *(const f32x4*)(E + eend);
        float ax = 0.f, ay = 0.f, az = 0.f, aw = 0.f;
        for (int i = 0; i <= len; ++i) {
            float a = at[i];
            f32x4 v = *(const f32x4*)(E + ebase + (long)i * EE);
            ax += v.x * a; ay += v.y * a; az += v.z * a; aw += v.w * a;
        }
        f32x4 sm = {ax, ay, az, aw};
        __builtin_nontemporal_store(se, (f32x4*)(O + obase));
        __builtin_nontemporal_store(ed, (f32x4*)(O + obase + 1024));
        __builtin_nontemporal_store(sm, (f32x4*)(O + obase + 2048));
    }
    // ---- phase B: mention-layer-1 row via linearity ----
    long rowi = (long)(b*SS + s);
    if (t < HP) {
        float acc = biases2[t]
                  + b2f(Pabc[((long)(b*TT + st)) * 480 + t])
                  + b2f(Pabc[((long)(b*TT + en)) * 480 + 160 + t]);
        const ushort* pc = Pabc + ((long)(b*TT + st)) * 480 + 320 + t;
        for (int i = 0; i <= len; ++i) acc += at[i] * b2f(pc[(long)i * 480]);
        acc = acc > 0.f ? acc : 0.f;
        h1m[rowi * KP2 + t] = f2b(acc);
    } else if (t < KP2) {
        h1m[rowi * KP2 + t] = 0;
    }
}

extern "C" void kernel_launch(void* const* d_in, const int* in_sizes, int n_in,
                              void* d_out, int out_size, void* d_ws, size_t ws_size,
                              hipStream_t stream)
{
    const void* embeds = d_in[0];
    const void* a_w1 = d_in[1];  const void* a_b1 = d_in[2];
    const void* a_w2 = d_in[3];  const void* a_b2 = d_in[4];
    const void* a_w3 = d_in[5];  const void* a_b3 = d_in[6];
    const void* s_w1 = d_in[7];  const void* s_b1 = d_in[8];
    const void* s_w2 = d_in[9];  const void* s_b2 = d_in[10];
    const void* s_w3 = d_in[11]; const void* s_b3 = d_in[12];
    const int* starts = (const int*)d_in[13];
    const int* lens   = (const int*)d_in[14];

    // workspace layout — ~30 MB
    char* ws = (char*)d_ws;
    int*    dflag = (int*)ws;                  ws += 256;
    ushort* Wbig  = (ushort*)ws;               ws += (size_t)NB*EE*2;        // 1.31 MB
    ushort* a_w2t = (ushort*)ws;               ws += (size_t)HP*KP2*2;       // 60 KB
    ushort* s_w2t = (ushort*)ws;               ws += (size_t)HP*KP2*2;       // 60 KB
    float*  biases = (float*)ws;               ws += (size_t)4*HP*4;         // 2.5 KB
    ushort* h1a  = (ushort*)ws;                ws += (size_t)NT*KP2*2;       // 6.3 MB
    ushort* Pabc = (ushort*)ws;                ws += (size_t)NT*480*2;       // 15.7 MB
    float*  attns = (float*)ws;                ws += (size_t)NT*4;           // 64 KB
    ushort* h1m  = (ushort*)ws;                ws += (size_t)NS*KP2*2;       // 6.1 MB

    detect_kernel<<<1, 1024, 0, stream>>>((const ushort*)embeds, dflag);
    prep_kernel<<<dim3(NB, 4), 256, 0, stream>>>(a_w1, s_w1, a_w2, s_w2,
                                                 a_b1, a_b2, s_b1, s_b2, dflag,
                                                 Wbig, a_w2t, s_w2t, biases);
    // token-level fused layer-1 GEMM (attn h1 + mention projections Pa,Pb,Pc)
    big_gemm_kernel<<<dim3(NT/64, 4), 256, 0, stream>>>(embeds, dflag, Wbig, biases, h1a, Pabc);
    // attn layer-2 + score (fused)
    gemm_relu_dot_kernel<<<NT/64, 256, 0, stream>>>(h1a, a_w2t, biases + HP,
                                                    a_w3, a_b3, dflag, attns, nullptr);
    // spans: output 0 + mention h1 via linearity (XCD-swizzled)
    span_kernel<<<NS, 256, 0, stream>>>(embeds, attns, starts, lens, d_out, dflag,
                                        Pabc, biases + 2*HP, h1m);
    // mention layer-2 + score (fused)
    gemm_relu_dot_kernel<<<NS/64, 256, 0, stream>>>(h1m, s_w2t, biases + 3*HP,
                                                    s_w3, s_b3, dflag, nullptr, d_out);
}